// Round 6
// baseline (354.809 us; speedup 1.0000x reference)
//
#include <hip/hip_runtime.h>
#include <hip/hip_bf16.h>

// ---------------------------------------------------------------------------
// DeformableSpatialEncoder on MI355X (gfx950)
//
// R5 insight (linearity collapse): deform output is linear in V and V is
// linear in A:
//   core_m[n] = mean_lq Σ_p softmax*bilinear*V[tok]
//             = ( Wfv_m · s_{n,m}  +  S_{n,m} · bfused_m ) / 196
//   s_{n,m}  = Σ_tok coeff_m[n][tok] · A[n,tok,:]   (196-dim contraction)
//   coeff_m[n][tok] = Σ_{lq,p} softmax*bilinear weights landing on tok
// -> Vbuf (22.5 MB write) and the gather kernel are ELIMINATED; the main
//    GEMM only needs the 48 off/aw output columns (N=128 instead of 896).
//
// Pipeline (N=64 images, Lq=196, D=768, heads=4, Dh=192, points=4):
//   1. stage:   im2col x->A bf16 [12544,768] + WembT/Wcat bf16 casts +
//               bfused[896] = Wcat@embed_b + orig_bias + zb zeros
//   2. wfuse:   Wfused bf16 [896,768] = Wcat @ Wemb (42-block GEMM)
//               rows 0..767 = value path (Wfv), 768..815 = off/aw, rest 0
//   3. gemm_oa: OA f32 [12544,64] = A @ Wfused[768:896]^T + bfused[768:]
//   4. percore: grid (64,4) — coeff scatter (LDS) -> s = coeff@A_n ->
//               core[n, m*192..] = (Wfv@s + S*bfused)/196
//   5. pooled = core @ outp_w^T + outp_b   (mean commuted with linear)
//   6. final  = pooled @ proj_w^T + proj_b -> d_out
// ---------------------------------------------------------------------------

using bf16 = __bf16;
typedef bf16  bf16x8 __attribute__((ext_vector_type(8)));
typedef float f32x4  __attribute__((ext_vector_type(4)));

#define N_IMG   64
#define LQ      196
#define DM      768
#define NH      4
#define DH      192
#define M_ROWS  (N_IMG * LQ)        // 12544
#define NCAT    896

// ---- workspace layout (bytes, all 256-aligned) ----
#define OFF_A      ((size_t)0)                     // 12544*768*2 = 19267584
#define OFF_WEMBT  (OFF_A     + 19267584)          // 768*768*2   = 1179648
#define OFF_WCAT   (OFF_WEMBT + 1179648)           // 896*768*2   = 1376256
#define OFF_WFUSE  (OFF_WCAT  + 1376256)           // 896*768*2   = 1376256
#define OFF_BFUSE  (OFF_WFUSE + 1376256)           // 4096
#define OFF_ZB     (OFF_BFUSE + 4096)              // 4096 (zero bias)
#define OFF_OA     (OFF_ZB    + 4096)              // 12544*64*4  = 3211264
#define OFF_CORE   (OFF_OA    + 3211264)           // 196608
#define OFF_POOL   (OFF_CORE  + 196608)            // 196608

__device__ __forceinline__ void gload_lds16(const bf16* g, bf16* l) {
#if __has_builtin(__builtin_amdgcn_global_load_lds)
  __builtin_amdgcn_global_load_lds(
      (const __attribute__((address_space(1))) void*)g,
      (__attribute__((address_space(3))) void*)l, 16, 0, 0);
#else
  *(bf16x8*)l = *(const bf16x8*)g;
#endif
}

// ---------------------------------------------------------------------------
// stage: blocks [0,9408)       im2col (coalesced both sides)
//        blocks [9408,12096)   prep: Wcat cast, WembT transposed cast, zb
//        blocks [12096,12124)  bfused: 8 threads per output dot
// ---------------------------------------------------------------------------
__global__ void stage_kernel(const float* __restrict__ x,
                             const float* __restrict__ embed_w,
                             const float* __restrict__ embed_b,
                             const float* __restrict__ value_w,
                             const float* __restrict__ off_w,
                             const float* __restrict__ aw_w,
                             const float* __restrict__ value_b,
                             const float* __restrict__ off_b,
                             const float* __restrict__ aw_b,
                             bf16* __restrict__ A,
                             bf16* __restrict__ WembT, bf16* __restrict__ Wcat,
                             float* __restrict__ bfused, float* __restrict__ zb) {
  const int bid = blockIdx.x;
  if (bid < 9408) {                       // ---- im2col ----
    const int t   = bid * 256 + threadIdx.x;   // < 12544*192 exactly
    const int row = t / 192;
    const int j   = t - row * 192;
    const int k   = j * 4;                // k = c*256 + p*16 + q, q%4==0
    const int c   = k >> 8;
    const int r   = k & 255;
    const int p   = r >> 4;
    const int q   = r & 15;
    const int n   = row / 196;
    const int lq  = row - n * 196;
    const int h   = lq / 14;
    const int w   = lq - h * 14;
    const float4 v = *(const float4*)(x +
        ((((size_t)n * 3 + c) * 224) + h * 16 + p) * 224 + w * 16 + q);
    bf16* dst = A + (size_t)row * DM + k;
    dst[0] = (bf16)v.x; dst[1] = (bf16)v.y; dst[2] = (bf16)v.z; dst[3] = (bf16)v.w;
    return;
  }
  if (bid < 12096) {                      // ---- prep ----
    const int idx = (bid - 9408) * 256 + threadIdx.x;   // < 688128 = 896*768
    {
      int rr = idx / DM, kk = idx - rr * DM;
      float v = 0.f;
      if (rr < 768)       v = value_w[idx];
      else if (rr < 800)  v = off_w[(rr - 768) * DM + kk];
      else if (rr < 816)  v = aw_w[(rr - 800) * DM + kk];
      Wcat[idx] = (bf16)v;
    }
    if (idx < DM * DM) {
      int kk = idx / DM, jj = idx - kk * DM;   // WembT[k][j] = embed_w[j][k]
      WembT[idx] = (bf16)embed_w[(size_t)jj * DM + kk];
    }
    if (idx < DM) zb[idx] = 0.f;
    return;
  }
  // ---- bfused ----
  const int t  = threadIdx.x;
  const int r  = (bid - 12096) * 32 + (t >> 3);   // 0..895
  const int t8 = t & 7;
  const float* src = nullptr;
  float badd = 0.f;
  if (r < 768)      { src = value_w + (size_t)r * DM;        badd = value_b[r]; }
  else if (r < 800) { src = off_w  + (size_t)(r - 768) * DM; badd = off_b[r - 768]; }
  else if (r < 816) { src = aw_w   + (size_t)(r - 800) * DM; badd = aw_b[r - 800]; }
  float s = 0.f;
  if (src) {
    for (int j = t8; j < DM; j += 8) s += src[j] * embed_b[j];
  }
#pragma unroll
  for (int o = 4; o >= 1; o >>= 1) s += __shfl_down(s, o, 8);
  if (t8 == 0) bfused[r] = (src ? s + badd : 0.f);
}

// ---------------------------------------------------------------------------
// gemm_bt: C[M,N] = A[M,K]bf16 @ B[N,K]bf16 ^T + bias[N]  (bf16 out)
// 128x128 tile, BK=64, 256 threads, mfma_f32_16x16x32_bf16.
// ---------------------------------------------------------------------------
__global__ void gemm_bt(const bf16* __restrict__ A, const bf16* __restrict__ B,
                        const float* __restrict__ bias, bf16* __restrict__ C,
                        int M, int N, int K) {
  __shared__ bf16 As[128 * 64];
  __shared__ bf16 Bs[128 * 64];

  const int tid  = threadIdx.x;
  const int wave = tid >> 6;
  const int lane = tid & 63;
  const int nBase = blockIdx.x * 128;
  const int mBase = blockIdx.y * 128;
  const int wm = wave & 1;
  const int wn = wave >> 1;
  const int quad = lane >> 4;
  const int r16  = lane & 15;

  const f32x4 zero = {0.f, 0.f, 0.f, 0.f};
  f32x4 acc[4][4];
#pragma unroll
  for (int mi = 0; mi < 4; ++mi)
#pragma unroll
    for (int ni = 0; ni < 4; ++ni) acc[mi][ni] = zero;

  const int srow = wave * 32 + (lane >> 3);
  const int scol = (lane & 7) * 8;
  const bf16* Ag = A + (size_t)(mBase + srow) * K + scol;
  const bf16* Bg = B + (size_t)(nBase + srow) * K + scol;
  bf16* Al = As + srow * 64 + scol;
  bf16* Bl = Bs + srow * 64 + scol;

  for (int kt = 0; kt < K; kt += 64) {
#pragma unroll
    for (int i = 0; i < 4; ++i) {
      gload_lds16(Ag + (size_t)(i * 8) * K + kt, Al + i * 8 * 64);
      gload_lds16(Bg + (size_t)(i * 8) * K + kt, Bl + i * 8 * 64);
    }
    __syncthreads();
#pragma unroll
    for (int kk = 0; kk < 64; kk += 32) {
      bf16x8 af[4], bfr[4];
#pragma unroll
      for (int mi = 0; mi < 4; ++mi)
        af[mi] = *(const bf16x8*)&As[(wm * 64 + mi * 16 + r16) * 64 + kk + quad * 8];
#pragma unroll
      for (int ni = 0; ni < 4; ++ni)
        bfr[ni] = *(const bf16x8*)&Bs[(wn * 64 + ni * 16 + r16) * 64 + kk + quad * 8];
#pragma unroll
      for (int mi = 0; mi < 4; ++mi)
#pragma unroll
        for (int ni = 0; ni < 4; ++ni)
          acc[mi][ni] = __builtin_amdgcn_mfma_f32_16x16x32_bf16(
              af[mi], bfr[ni], acc[mi][ni], 0, 0, 0);
    }
    __syncthreads();
  }

#pragma unroll
  for (int ni = 0; ni < 4; ++ni) {
    const int col = nBase + wn * 64 + ni * 16 + r16;
    const float bv = bias[col];
#pragma unroll
    for (int mi = 0; mi < 4; ++mi) {
      const int row0 = mBase + wm * 64 + mi * 16 + quad * 4;
#pragma unroll
      for (int rr = 0; rr < 4; ++rr) {
        C[(size_t)(row0 + rr) * N + col] = (bf16)(acc[mi][ni][rr] + bv);
      }
    }
  }
}

// ---------------------------------------------------------------------------
// gemm_oa: OA[M,64] f32 = A[M,768] @ B128[128,768]^T + bias[128], cols<64 kept.
// B128 = Wfused+768*768 (rows 768..895; 816+ are zero). grid(98), N fixed 128.
// ---------------------------------------------------------------------------
__global__ void gemm_oa(const bf16* __restrict__ A, const bf16* __restrict__ B,
                        const float* __restrict__ bias, float* __restrict__ OA,
                        int K) {
  __shared__ bf16 As[128 * 64];
  __shared__ bf16 Bs[128 * 64];

  const int tid  = threadIdx.x;
  const int wave = tid >> 6;
  const int lane = tid & 63;
  const int mBase = blockIdx.x * 128;
  const int wm = wave & 1;
  const int wn = wave >> 1;
  const int quad = lane >> 4;
  const int r16  = lane & 15;

  const f32x4 zero = {0.f, 0.f, 0.f, 0.f};
  f32x4 acc[4][4];
#pragma unroll
  for (int mi = 0; mi < 4; ++mi)
#pragma unroll
    for (int ni = 0; ni < 4; ++ni) acc[mi][ni] = zero;

  const int srow = wave * 32 + (lane >> 3);
  const int scol = (lane & 7) * 8;
  const bf16* Ag = A + (size_t)(mBase + srow) * K + scol;
  const bf16* Bg = B + (size_t)srow * K + scol;
  bf16* Al = As + srow * 64 + scol;
  bf16* Bl = Bs + srow * 64 + scol;

  for (int kt = 0; kt < K; kt += 64) {
#pragma unroll
    for (int i = 0; i < 4; ++i) {
      gload_lds16(Ag + (size_t)(i * 8) * K + kt, Al + i * 8 * 64);
      gload_lds16(Bg + (size_t)(i * 8) * K + kt, Bl + i * 8 * 64);
    }
    __syncthreads();
#pragma unroll
    for (int kk = 0; kk < 64; kk += 32) {
      bf16x8 af[4], bfr[4];
#pragma unroll
      for (int mi = 0; mi < 4; ++mi)
        af[mi] = *(const bf16x8*)&As[(wm * 64 + mi * 16 + r16) * 64 + kk + quad * 8];
#pragma unroll
      for (int ni = 0; ni < 4; ++ni)
        bfr[ni] = *(const bf16x8*)&Bs[(wn * 64 + ni * 16 + r16) * 64 + kk + quad * 8];
#pragma unroll
      for (int mi = 0; mi < 4; ++mi)
#pragma unroll
        for (int ni = 0; ni < 4; ++ni)
          acc[mi][ni] = __builtin_amdgcn_mfma_f32_16x16x32_bf16(
              af[mi], bfr[ni], acc[mi][ni], 0, 0, 0);
    }
    __syncthreads();
  }

#pragma unroll
  for (int ni = 0; ni < 4; ++ni) {
    const int col = wn * 64 + ni * 16 + r16;
    if (col >= 64) continue;
    const float bv = bias[col];
#pragma unroll
    for (int mi = 0; mi < 4; ++mi) {
      const int row0 = mBase + wm * 64 + mi * 16 + quad * 4;
#pragma unroll
      for (int rr = 0; rr < 4; ++rr) {
        OA[(size_t)(row0 + rr) * 64 + col] = acc[mi][ni][rr] + bv;
      }
    }
  }
}

// ---------------------------------------------------------------------------
// percore: grid (64, 4) = (image n, head m), block 256.
// A) scatter softmax*bilinear weights into coeff[196] (LDS atomics), S=Σcoeff
// B) s[768] = Σ_tok coeff[tok] * A[n,tok,:]        (LDS)
// C) core[n][m*192+d] = (Wfv[m*192+d]·s + S*bfused[m*192+d]) / 196
// ---------------------------------------------------------------------------
__global__ void percore_kernel(const bf16* __restrict__ A,
                               const float* __restrict__ OA,
                               const bf16* __restrict__ Wfused,
                               const float* __restrict__ bfused,
                               float* __restrict__ core) {
  __shared__ float sC[LQ];     // coeff bins
  __shared__ float sS[DM];     // s vector
  __shared__ float sSum;

  const int n = blockIdx.x;
  const int m = blockIdx.y;
  const int tid = threadIdx.x;

  // init
  if (tid < LQ) sC[tid] = 0.f;
  if (tid == 0) sSum = 0.f;
  __syncthreads();

  // --- Phase A: 784 (lq,p) scatter ---
  const float* oa = OA + (size_t)n * LQ * 64;
  for (int t = tid; t < LQ * 4; t += 256) {
    const int lq = t >> 2, p = t & 3;
    const float* row = oa + (size_t)lq * 64;
    const float l0 = row[32 + m * 4 + 0];
    const float l1 = row[32 + m * 4 + 1];
    const float l2 = row[32 + m * 4 + 2];
    const float l3 = row[32 + m * 4 + 3];
    const float mx = fmaxf(fmaxf(l0, l1), fmaxf(l2, l3));
    const float e0 = __expf(l0 - mx), e1 = __expf(l1 - mx);
    const float e2 = __expf(l2 - mx), e3 = __expf(l3 - mx);
    const float inv = 1.f / (e0 + e1 + e2 + e3);
    const float ep[4] = {e0, e1, e2, e3};
    const float ew = ep[p] * inv;

    const int h = lq / 14, w = lq - (lq / 14) * 14;
    const float px = (float)w * (14.f / 13.f) - 0.5f + row[(m * 4 + p) * 2 + 0];
    const float py = (float)h * (14.f / 13.f) - 0.5f + row[(m * 4 + p) * 2 + 1];
    const float fx = floorf(px), fy = floorf(py);
    const int x0 = (int)fx, y0 = (int)fy;
    const float wx1 = px - fx, wy1 = py - fy;
    const float wx0 = 1.f - wx1, wy0 = 1.f - wy1;

    const bool vx0 = (x0 >= 0) & (x0 < 14);
    const bool vx1 = (x0 >= -1) & (x0 < 13);
    const bool vy0 = (y0 >= 0) & (y0 < 14);
    const bool vy1 = (y0 >= -1) & (y0 < 13);
    const int cx0 = min(max(x0, 0), 13),      cx1 = min(max(x0 + 1, 0), 13);
    const int cy0 = min(max(y0, 0), 13) * 14, cy1 = min(max(y0 + 1, 0), 13) * 14;

    atomicAdd(&sC[cy0 + cx0], (vx0 & vy0) ? ew * wx0 * wy0 : 0.f);
    atomicAdd(&sC[cy0 + cx1], (vx1 & vy0) ? ew * wx1 * wy0 : 0.f);
    atomicAdd(&sC[cy1 + cx0], (vx0 & vy1) ? ew * wx0 * wy1 : 0.f);
    atomicAdd(&sC[cy1 + cx1], (vx1 & vy1) ? ew * wx1 * wy1 : 0.f);
  }
  __syncthreads();
  if (tid < LQ) atomicAdd(&sSum, sC[tid]);
  __syncthreads();

  // --- Phase B: s = coeff @ A_n ---
  {
    const bf16* an = A + (size_t)n * LQ * DM;
    float a0 = 0.f, a1 = 0.f, a2 = 0.f;
    const int c0 = tid, c1 = tid + 256, c2 = tid + 512;
    for (int tok = 0; tok < LQ; ++tok) {
      const float cf = sC[tok];
      const bf16* ar = an + (size_t)tok * DM;
      a0 += cf * (float)ar[c0];
      a1 += cf * (float)ar[c1];
      a2 += cf * (float)ar[c2];
    }
    sS[c0] = a0; sS[c1] = a1; sS[c2] = a2;
  }
  __syncthreads();

  // --- Phase C: core channels for this head ---
  if (tid < DH) {
    const int ch = m * DH + tid;
    const bf16* wr = Wfused + (size_t)ch * DM;
    float acc = 0.f;
    for (int k = 0; k < DM; k += 8) {
      const bf16x8 wv = *(const bf16x8*)(wr + k);
#pragma unroll
      for (int j = 0; j < 8; ++j) acc += (float)wv[j] * sS[k + j];
    }
    core[(size_t)n * DM + ch] = (acc + sSum * bfused[ch]) * (1.f / 196.f);
  }
}

// ---------------------------------------------------------------------------
// small_linear_b: out[n][d] = in[n]·W[d] + b[d], 16 images per block (ILP).
// grid (3, 4), block 256.
// ---------------------------------------------------------------------------
__global__ void small_linear_b(const float* __restrict__ in,
                               const float* __restrict__ W,
                               const float* __restrict__ b,
                               float* __restrict__ out) {
  const int d  = blockIdx.x * 256 + threadIdx.x;
  const int n0 = blockIdx.y * 16;
  const float4* w4 = (const float4*)(W + (size_t)d * DM);
  float acc[16];
#pragma unroll
  for (int j = 0; j < 16; ++j) acc[j] = 0.f;
  for (int k = 0; k < DM / 4; ++k) {
    const float4 w = w4[k];
#pragma unroll
    for (int j = 0; j < 16; ++j) {
      const float4 a = *(const float4*)(in + (size_t)(n0 + j) * DM + k * 4);
      acc[j] += a.x * w.x + a.y * w.y + a.z * w.z + a.w * w.w;
    }
  }
  const float bv = b[d];
#pragma unroll
  for (int j = 0; j < 16; ++j) out[(size_t)(n0 + j) * DM + d] = acc[j] + bv;
}

// ---------------------------------------------------------------------------
extern "C" void kernel_launch(void* const* d_in, const int* in_sizes, int n_in,
                              void* d_out, int out_size, void* d_ws, size_t ws_size,
                              hipStream_t stream) {
  const float* x       = (const float*)d_in[0];
  const float* embed_w = (const float*)d_in[1];
  const float* embed_b = (const float*)d_in[2];
  const float* value_w = (const float*)d_in[3];
  const float* value_b = (const float*)d_in[4];
  const float* off_w   = (const float*)d_in[5];
  const float* off_b   = (const float*)d_in[6];
  const float* aw_w    = (const float*)d_in[7];
  const float* aw_b    = (const float*)d_in[8];
  const float* outp_w  = (const float*)d_in[9];
  const float* outp_b  = (const float*)d_in[10];
  const float* proj_w  = (const float*)d_in[11];
  const float* proj_b  = (const float*)d_in[12];
  float* out = (float*)d_out;

  char* ws = (char*)d_ws;
  bf16*  A      = (bf16*)(ws + OFF_A);
  bf16*  WembT  = (bf16*)(ws + OFF_WEMBT);
  bf16*  Wcat   = (bf16*)(ws + OFF_WCAT);
  bf16*  Wfused = (bf16*)(ws + OFF_WFUSE);
  float* bfused = (float*)(ws + OFF_BFUSE);
  float* zb     = (float*)(ws + OFF_ZB);
  float* OA     = (float*)(ws + OFF_OA);
  float* core   = (float*)(ws + OFF_CORE);
  float* pooled = (float*)(ws + OFF_POOL);

  stage_kernel<<<dim3(12124), dim3(256), 0, stream>>>(
      x, embed_w, embed_b, value_w, off_w, aw_w, value_b, off_b, aw_b,
      A, WembT, Wcat, bfused, zb);

  // Wfused[r][k] = (Wcat@Wemb)[r][k]
  gemm_bt<<<dim3(DM / 128, NCAT / 128), dim3(256), 0, stream>>>(
      Wcat, WembT, zb, Wfused, NCAT, DM, DM);

  gemm_oa<<<dim3(M_ROWS / 128), dim3(256), 0, stream>>>(
      A, Wfused + (size_t)768 * DM, bfused + 768, OA, DM);

  percore_kernel<<<dim3(N_IMG, NH), dim3(256), 0, stream>>>(
      A, OA, Wfused, bfused, core);

  small_linear_b<<<dim3(3, 4), dim3(256), 0, stream>>>(core, outp_w, outp_b, pooled);
  small_linear_b<<<dim3(3, 4), dim3(256), 0, stream>>>(pooled, proj_w, proj_b, out);
}

// Round 7
// 248.612 us; speedup vs baseline: 1.4272x; 1.4272x over previous
//
#include <hip/hip_runtime.h>
#include <hip/hip_bf16.h>

// ---------------------------------------------------------------------------
// DeformableSpatialEncoder on MI355X (gfx950)
//
// Linearity-collapsed pipeline (R5/R6):
//   core_m[n] = ( Wfv_m · s_{n,m} + S_{n,m} · bfused_m ) / 196
//   s_{n,m}  = Σ_tok coeff_m[n][tok] · A[n,tok,:]
//   coeff    = scattered softmax×bilinear weights (needs only off/aw cols)
// -> no Vbuf, no value gather; main GEMM is N=128 (off/aw logits only).
//
// R7 fixes: (a) small_linear reverted to grid(64,3) one-dot-per-thread
// (R6's 12-block version was latency-bound at 84 µs, occupancy 0.5%);
// (b) percore Phase B: 4 waves × 49-token quarters, 12 acc/thread ILP.
//
// Pipeline:
//   1. stage:   im2col x->A bf16 [12544,768] + WembT/Wcat casts + bfused
//   2. wfuse:   Wfused bf16 [896,768] = Wcat @ Wemb
//   3. gemm_oa: OA f32 [12544,64] = A @ Wfused[768:896]^T + bfused[768:]
//   4. percore: grid (64,4) — coeff scatter -> s = coeff@A_n -> core
//   5. pooled = core @ outp_w^T + outp_b
//   6. final  = pooled @ proj_w^T + proj_b -> d_out
// ---------------------------------------------------------------------------

using bf16 = __bf16;
typedef bf16  bf16x8 __attribute__((ext_vector_type(8)));
typedef float f32x4  __attribute__((ext_vector_type(4)));

#define N_IMG   64
#define LQ      196
#define DM      768
#define NH      4
#define DH      192
#define M_ROWS  (N_IMG * LQ)        // 12544
#define NCAT    896

// ---- workspace layout (bytes, all 256-aligned) ----
#define OFF_A      ((size_t)0)                     // 12544*768*2 = 19267584
#define OFF_WEMBT  (OFF_A     + 19267584)          // 768*768*2   = 1179648
#define OFF_WCAT   (OFF_WEMBT + 1179648)           // 896*768*2   = 1376256
#define OFF_WFUSE  (OFF_WCAT  + 1376256)           // 896*768*2   = 1376256
#define OFF_BFUSE  (OFF_WFUSE + 1376256)           // 4096
#define OFF_ZB     (OFF_BFUSE + 4096)              // 4096 (zero bias)
#define OFF_OA     (OFF_ZB    + 4096)              // 12544*64*4  = 3211264
#define OFF_CORE   (OFF_OA    + 3211264)           // 196608
#define OFF_POOL   (OFF_CORE  + 196608)            // 196608

__device__ __forceinline__ void gload_lds16(const bf16* g, bf16* l) {
#if __has_builtin(__builtin_amdgcn_global_load_lds)
  __builtin_amdgcn_global_load_lds(
      (const __attribute__((address_space(1))) void*)g,
      (__attribute__((address_space(3))) void*)l, 16, 0, 0);
#else
  *(bf16x8*)l = *(const bf16x8*)g;
#endif
}

// ---------------------------------------------------------------------------
// stage: blocks [0,9408)       im2col (coalesced both sides)
//        blocks [9408,12096)   prep: Wcat cast, WembT transposed cast, zb
//        blocks [12096,12124)  bfused: 8 threads per output dot
// ---------------------------------------------------------------------------
__global__ void stage_kernel(const float* __restrict__ x,
                             const float* __restrict__ embed_w,
                             const float* __restrict__ embed_b,
                             const float* __restrict__ value_w,
                             const float* __restrict__ off_w,
                             const float* __restrict__ aw_w,
                             const float* __restrict__ value_b,
                             const float* __restrict__ off_b,
                             const float* __restrict__ aw_b,
                             bf16* __restrict__ A,
                             bf16* __restrict__ WembT, bf16* __restrict__ Wcat,
                             float* __restrict__ bfused, float* __restrict__ zb) {
  const int bid = blockIdx.x;
  if (bid < 9408) {                       // ---- im2col ----
    const int t   = bid * 256 + threadIdx.x;   // < 12544*192 exactly
    const int row = t / 192;
    const int j   = t - row * 192;
    const int k   = j * 4;                // k = c*256 + p*16 + q, q%4==0
    const int c   = k >> 8;
    const int r   = k & 255;
    const int p   = r >> 4;
    const int q   = r & 15;
    const int n   = row / 196;
    const int lq  = row - n * 196;
    const int h   = lq / 14;
    const int w   = lq - h * 14;
    const float4 v = *(const float4*)(x +
        ((((size_t)n * 3 + c) * 224) + h * 16 + p) * 224 + w * 16 + q);
    bf16* dst = A + (size_t)row * DM + k;
    dst[0] = (bf16)v.x; dst[1] = (bf16)v.y; dst[2] = (bf16)v.z; dst[3] = (bf16)v.w;
    return;
  }
  if (bid < 12096) {                      // ---- prep ----
    const int idx = (bid - 9408) * 256 + threadIdx.x;   // < 688128 = 896*768
    {
      int rr = idx / DM, kk = idx - rr * DM;
      float v = 0.f;
      if (rr < 768)       v = value_w[idx];
      else if (rr < 800)  v = off_w[(rr - 768) * DM + kk];
      else if (rr < 816)  v = aw_w[(rr - 800) * DM + kk];
      Wcat[idx] = (bf16)v;
    }
    if (idx < DM * DM) {
      int kk = idx / DM, jj = idx - kk * DM;   // WembT[k][j] = embed_w[j][k]
      WembT[idx] = (bf16)embed_w[(size_t)jj * DM + kk];
    }
    if (idx < DM) zb[idx] = 0.f;
    return;
  }
  // ---- bfused ----
  const int t  = threadIdx.x;
  const int r  = (bid - 12096) * 32 + (t >> 3);   // 0..895
  const int t8 = t & 7;
  const float* src = nullptr;
  float badd = 0.f;
  if (r < 768)      { src = value_w + (size_t)r * DM;        badd = value_b[r]; }
  else if (r < 800) { src = off_w  + (size_t)(r - 768) * DM; badd = off_b[r - 768]; }
  else if (r < 816) { src = aw_w   + (size_t)(r - 800) * DM; badd = aw_b[r - 800]; }
  float s = 0.f;
  if (src) {
    for (int j = t8; j < DM; j += 8) s += src[j] * embed_b[j];
  }
#pragma unroll
  for (int o = 4; o >= 1; o >>= 1) s += __shfl_down(s, o, 8);
  if (t8 == 0) bfused[r] = (src ? s + badd : 0.f);
}

// ---------------------------------------------------------------------------
// gemm_bt: C[M,N] = A[M,K]bf16 @ B[N,K]bf16 ^T + bias[N]  (bf16 out)
// 128x128 tile, BK=64, 256 threads, mfma_f32_16x16x32_bf16.
// ---------------------------------------------------------------------------
__global__ void gemm_bt(const bf16* __restrict__ A, const bf16* __restrict__ B,
                        const float* __restrict__ bias, bf16* __restrict__ C,
                        int M, int N, int K) {
  __shared__ bf16 As[128 * 64];
  __shared__ bf16 Bs[128 * 64];

  const int tid  = threadIdx.x;
  const int wave = tid >> 6;
  const int lane = tid & 63;
  const int nBase = blockIdx.x * 128;
  const int mBase = blockIdx.y * 128;
  const int wm = wave & 1;
  const int wn = wave >> 1;
  const int quad = lane >> 4;
  const int r16  = lane & 15;

  const f32x4 zero = {0.f, 0.f, 0.f, 0.f};
  f32x4 acc[4][4];
#pragma unroll
  for (int mi = 0; mi < 4; ++mi)
#pragma unroll
    for (int ni = 0; ni < 4; ++ni) acc[mi][ni] = zero;

  const int srow = wave * 32 + (lane >> 3);
  const int scol = (lane & 7) * 8;
  const bf16* Ag = A + (size_t)(mBase + srow) * K + scol;
  const bf16* Bg = B + (size_t)(nBase + srow) * K + scol;
  bf16* Al = As + srow * 64 + scol;
  bf16* Bl = Bs + srow * 64 + scol;

  for (int kt = 0; kt < K; kt += 64) {
#pragma unroll
    for (int i = 0; i < 4; ++i) {
      gload_lds16(Ag + (size_t)(i * 8) * K + kt, Al + i * 8 * 64);
      gload_lds16(Bg + (size_t)(i * 8) * K + kt, Bl + i * 8 * 64);
    }
    __syncthreads();
#pragma unroll
    for (int kk = 0; kk < 64; kk += 32) {
      bf16x8 af[4], bfr[4];
#pragma unroll
      for (int mi = 0; mi < 4; ++mi)
        af[mi] = *(const bf16x8*)&As[(wm * 64 + mi * 16 + r16) * 64 + kk + quad * 8];
#pragma unroll
      for (int ni = 0; ni < 4; ++ni)
        bfr[ni] = *(const bf16x8*)&Bs[(wn * 64 + ni * 16 + r16) * 64 + kk + quad * 8];
#pragma unroll
      for (int mi = 0; mi < 4; ++mi)
#pragma unroll
        for (int ni = 0; ni < 4; ++ni)
          acc[mi][ni] = __builtin_amdgcn_mfma_f32_16x16x32_bf16(
              af[mi], bfr[ni], acc[mi][ni], 0, 0, 0);
    }
    __syncthreads();
  }

#pragma unroll
  for (int ni = 0; ni < 4; ++ni) {
    const int col = nBase + wn * 64 + ni * 16 + r16;
    const float bv = bias[col];
#pragma unroll
    for (int mi = 0; mi < 4; ++mi) {
      const int row0 = mBase + wm * 64 + mi * 16 + quad * 4;
#pragma unroll
      for (int rr = 0; rr < 4; ++rr) {
        C[(size_t)(row0 + rr) * N + col] = (bf16)(acc[mi][ni][rr] + bv);
      }
    }
  }
}

// ---------------------------------------------------------------------------
// gemm_oa: OA[M,64] f32 = A[M,768] @ B128[128,768]^T + bias[128], cols<64 kept.
// ---------------------------------------------------------------------------
__global__ void gemm_oa(const bf16* __restrict__ A, const bf16* __restrict__ B,
                        const float* __restrict__ bias, float* __restrict__ OA,
                        int K) {
  __shared__ bf16 As[128 * 64];
  __shared__ bf16 Bs[128 * 64];

  const int tid  = threadIdx.x;
  const int wave = tid >> 6;
  const int lane = tid & 63;
  const int mBase = blockIdx.x * 128;
  const int wm = wave & 1;
  const int wn = wave >> 1;
  const int quad = lane >> 4;
  const int r16  = lane & 15;

  const f32x4 zero = {0.f, 0.f, 0.f, 0.f};
  f32x4 acc[4][4];
#pragma unroll
  for (int mi = 0; mi < 4; ++mi)
#pragma unroll
    for (int ni = 0; ni < 4; ++ni) acc[mi][ni] = zero;

  const int srow = wave * 32 + (lane >> 3);
  const int scol = (lane & 7) * 8;
  const bf16* Ag = A + (size_t)(mBase + srow) * K + scol;
  const bf16* Bg = B + (size_t)srow * K + scol;
  bf16* Al = As + srow * 64 + scol;
  bf16* Bl = Bs + srow * 64 + scol;

  for (int kt = 0; kt < K; kt += 64) {
#pragma unroll
    for (int i = 0; i < 4; ++i) {
      gload_lds16(Ag + (size_t)(i * 8) * K + kt, Al + i * 8 * 64);
      gload_lds16(Bg + (size_t)(i * 8) * K + kt, Bl + i * 8 * 64);
    }
    __syncthreads();
#pragma unroll
    for (int kk = 0; kk < 64; kk += 32) {
      bf16x8 af[4], bfr[4];
#pragma unroll
      for (int mi = 0; mi < 4; ++mi)
        af[mi] = *(const bf16x8*)&As[(wm * 64 + mi * 16 + r16) * 64 + kk + quad * 8];
#pragma unroll
      for (int ni = 0; ni < 4; ++ni)
        bfr[ni] = *(const bf16x8*)&Bs[(wn * 64 + ni * 16 + r16) * 64 + kk + quad * 8];
#pragma unroll
      for (int mi = 0; mi < 4; ++mi)
#pragma unroll
        for (int ni = 0; ni < 4; ++ni)
          acc[mi][ni] = __builtin_amdgcn_mfma_f32_16x16x32_bf16(
              af[mi], bfr[ni], acc[mi][ni], 0, 0, 0);
    }
    __syncthreads();
  }

#pragma unroll
  for (int ni = 0; ni < 4; ++ni) {
    const int col = wn * 64 + ni * 16 + r16;
    if (col >= 64) continue;
    const float bv = bias[col];
#pragma unroll
    for (int mi = 0; mi < 4; ++mi) {
      const int row0 = mBase + wm * 64 + mi * 16 + quad * 4;
#pragma unroll
      for (int rr = 0; rr < 4; ++rr) {
        OA[(size_t)(row0 + rr) * 64 + col] = acc[mi][ni][rr] + bv;
      }
    }
  }
}

// ---------------------------------------------------------------------------
// percore: grid (64, 4) = (image n, head m), block 256.
// A) scatter softmax*bilinear weights into coeff[196] (LDS atomics), S=Σcoeff
// B) s[768] = Σ_tok coeff[tok]*A[n,tok,:] — wave q owns tokens [q*49,q*49+49),
//    each thread 12 channels (lane + 64*j): 12-way ILP, 49-deep chain, then
//    LDS partial reduce over the 4 waves.
// C) core[n][m*192+d] = (Wfv[m*192+d]·s + S*bfused[m*192+d]) / 196
// ---------------------------------------------------------------------------
__global__ void percore_kernel(const bf16* __restrict__ A,
                               const float* __restrict__ OA,
                               const bf16* __restrict__ Wfused,
                               const float* __restrict__ bfused,
                               float* __restrict__ core) {
  __shared__ float sC[LQ];       // coeff bins
  __shared__ float sP[4][DM];    // per-wave partials
  __shared__ float sS[DM];       // s vector
  __shared__ float sSum;

  const int n = blockIdx.x;
  const int m = blockIdx.y;
  const int tid = threadIdx.x;

  if (tid < LQ) sC[tid] = 0.f;
  if (tid == 0) sSum = 0.f;
  __syncthreads();

  // --- Phase A: 784 (lq,p) scatter ---
  const float* oa = OA + (size_t)n * LQ * 64;
  for (int t = tid; t < LQ * 4; t += 256) {
    const int lq = t >> 2, p = t & 3;
    const float* row = oa + (size_t)lq * 64;
    const float l0 = row[32 + m * 4 + 0];
    const float l1 = row[32 + m * 4 + 1];
    const float l2 = row[32 + m * 4 + 2];
    const float l3 = row[32 + m * 4 + 3];
    const float mx = fmaxf(fmaxf(l0, l1), fmaxf(l2, l3));
    const float e0 = __expf(l0 - mx), e1 = __expf(l1 - mx);
    const float e2 = __expf(l2 - mx), e3 = __expf(l3 - mx);
    const float inv = 1.f / (e0 + e1 + e2 + e3);
    const float ep[4] = {e0, e1, e2, e3};
    const float ew = ep[p] * inv;

    const int h = lq / 14, w = lq - (lq / 14) * 14;
    const float px = (float)w * (14.f / 13.f) - 0.5f + row[(m * 4 + p) * 2 + 0];
    const float py = (float)h * (14.f / 13.f) - 0.5f + row[(m * 4 + p) * 2 + 1];
    const float fx = floorf(px), fy = floorf(py);
    const int x0 = (int)fx, y0 = (int)fy;
    const float wx1 = px - fx, wy1 = py - fy;
    const float wx0 = 1.f - wx1, wy0 = 1.f - wy1;

    const bool vx0 = (x0 >= 0) & (x0 < 14);
    const bool vx1 = (x0 >= -1) & (x0 < 13);
    const bool vy0 = (y0 >= 0) & (y0 < 14);
    const bool vy1 = (y0 >= -1) & (y0 < 13);
    const int cx0 = min(max(x0, 0), 13),      cx1 = min(max(x0 + 1, 0), 13);
    const int cy0 = min(max(y0, 0), 13) * 14, cy1 = min(max(y0 + 1, 0), 13) * 14;

    atomicAdd(&sC[cy0 + cx0], (vx0 & vy0) ? ew * wx0 * wy0 : 0.f);
    atomicAdd(&sC[cy0 + cx1], (vx1 & vy0) ? ew * wx1 * wy0 : 0.f);
    atomicAdd(&sC[cy1 + cx0], (vx0 & vy1) ? ew * wx0 * wy1 : 0.f);
    atomicAdd(&sC[cy1 + cx1], (vx1 & vy1) ? ew * wx1 * wy1 : 0.f);
  }
  __syncthreads();
  if (tid < LQ) atomicAdd(&sSum, sC[tid]);

  // --- Phase B: s = coeff @ A_n, tok-split across waves ---
  {
    const int q = tid >> 6, lane = tid & 63;
    const bf16* an = A + (size_t)n * LQ * DM;
    float acc[12];
#pragma unroll
    for (int j = 0; j < 12; ++j) acc[j] = 0.f;
    const int t0 = q * 49;
    for (int tok = t0; tok < t0 + 49; ++tok) {
      const float cf = sC[tok];
      const bf16* ar = an + (size_t)tok * DM + lane;
#pragma unroll
      for (int j = 0; j < 12; ++j) acc[j] += cf * (float)ar[64 * j];
    }
#pragma unroll
    for (int j = 0; j < 12; ++j) sP[q][lane + 64 * j] = acc[j];
  }
  __syncthreads();
  for (int c = tid; c < DM; c += 256)
    sS[c] = sP[0][c] + sP[1][c] + sP[2][c] + sP[3][c];
  __syncthreads();

  // --- Phase C: core channels for this head ---
  if (tid < DH) {
    const int ch = m * DH + tid;
    const bf16* wr = Wfused + (size_t)ch * DM;
    float acc = 0.f;
    for (int k = 0; k < DM; k += 8) {
      const bf16x8 wv = *(const bf16x8*)(wr + k);
#pragma unroll
      for (int j = 0; j < 8; ++j) acc += (float)wv[j] * sS[k + j];
    }
    core[(size_t)n * DM + ch] = (acc + sSum * bfused[ch]) * (1.f / 196.f);
  }
}

// ---------------------------------------------------------------------------
// small_linear: out[n][d] = in[n]·W[d] + b[d].  grid (64,3), block 256.
// (R6's 12-block batched version was latency-bound: 84 µs, occ 0.5%.)
// ---------------------------------------------------------------------------
__global__ void small_linear(const float* __restrict__ in,
                             const float* __restrict__ W,
                             const float* __restrict__ b,
                             float* __restrict__ out) {
  const int n = blockIdx.x;
  const int d = blockIdx.y * 256 + threadIdx.x;
  const float4* a4 = (const float4*)(in + (size_t)n * DM);
  const float4* w4 = (const float4*)(W + (size_t)d * DM);
  float acc = 0.f;
#pragma unroll 4
  for (int k = 0; k < DM / 4; ++k) {
    float4 a = a4[k], w = w4[k];
    acc += a.x * w.x + a.y * w.y + a.z * w.z + a.w * w.w;
  }
  out[(size_t)n * DM + d] = acc + b[d];
}

// ---------------------------------------------------------------------------
extern "C" void kernel_launch(void* const* d_in, const int* in_sizes, int n_in,
                              void* d_out, int out_size, void* d_ws, size_t ws_size,
                              hipStream_t stream) {
  const float* x       = (const float*)d_in[0];
  const float* embed_w = (const float*)d_in[1];
  const float* embed_b = (const float*)d_in[2];
  const float* value_w = (const float*)d_in[3];
  const float* value_b = (const float*)d_in[4];
  const float* off_w   = (const float*)d_in[5];
  const float* off_b   = (const float*)d_in[6];
  const float* aw_w    = (const float*)d_in[7];
  const float* aw_b    = (const float*)d_in[8];
  const float* outp_w  = (const float*)d_in[9];
  const float* outp_b  = (const float*)d_in[10];
  const float* proj_w  = (const float*)d_in[11];
  const float* proj_b  = (const float*)d_in[12];
  float* out = (float*)d_out;

  char* ws = (char*)d_ws;
  bf16*  A      = (bf16*)(ws + OFF_A);
  bf16*  WembT  = (bf16*)(ws + OFF_WEMBT);
  bf16*  Wcat   = (bf16*)(ws + OFF_WCAT);
  bf16*  Wfused = (bf16*)(ws + OFF_WFUSE);
  float* bfused = (float*)(ws + OFF_BFUSE);
  float* zb     = (float*)(ws + OFF_ZB);
  float* OA     = (float*)(ws + OFF_OA);
  float* core   = (float*)(ws + OFF_CORE);
  float* pooled = (float*)(ws + OFF_POOL);

  stage_kernel<<<dim3(12124), dim3(256), 0, stream>>>(
      x, embed_w, embed_b, value_w, off_w, aw_w, value_b, off_b, aw_b,
      A, WembT, Wcat, bfused, zb);

  gemm_bt<<<dim3(DM / 128, NCAT / 128), dim3(256), 0, stream>>>(
      Wcat, WembT, zb, Wfused, NCAT, DM, DM);

  gemm_oa<<<dim3(M_ROWS / 128), dim3(256), 0, stream>>>(
      A, Wfused + (size_t)768 * DM, bfused + 768, OA, DM);

  percore_kernel<<<dim3(N_IMG, NH), dim3(256), 0, stream>>>(
      A, OA, Wfused, bfused, core);

  small_linear<<<dim3(64, 3), dim3(256), 0, stream>>>(core, outp_w, outp_b, pooled);
  small_linear<<<dim3(64, 3), dim3(256), 0, stream>>>(pooled, proj_w, proj_b, out);
}